// Round 7
// baseline (240.192 us; speedup 1.0000x reference)
//
#include <hip/hip_runtime.h>
#include <math.h>

#define NREL 500
#define CAP  256
#define NEDGE 53200   // qlc [0,25600) qrc [25600,51200) slc [51200,52200) srcn [52200,53200)

__device__ __forceinline__ float sigm(float x) { return 1.0f / (1.0f + __expf(-x)); }
__device__ __forceinline__ unsigned bf16_rne(float x) {
    unsigned b = __float_as_uint(x);
    return (b + 0x7fffu + ((b >> 16) & 1u)) >> 16;
}

// ws layout (float offsets), ~8 MiB total (known-safe: R5 ran 13.5 MiB)
#define OFF_WHHP   0              // 128*512 uint (bf16 pairs, live cols)
#define OFF_WIHP   65536          // 64*512 uint
#define OFF_QG     98304          // 128*128
#define OFF_SG     114688         // 5*128
#define OFF_STAGE  115328         // 53200*32 uint (bf16 pairs per edge row)

// ---------------------------------------------------------------------------
// K1 k_gather: 500 blocks x 256 threads (4 waves), launch_bounds(256,2) so the
// per-lane R row (64 VGPRs) does NOT spill (R5 lesson: default bounds gave
// VGPR=40 -> full spill -> 69us). Per block r:
//   (a) lane i holds R[r][i][0:64] in registers
//   (b) self-scan all 53200 edges (conn L2-resident), collect rel==r in LDS
//   (c) per edge (1/wave): wave-uniform e-loads, 2 indep fma chains,
//       write stage row as bf16 pairs (exactly-once per edge, no zero-init)
//   (d) fold in the lstm weight pack (<=1 elem/thread over the grid)
// ---------------------------------------------------------------------------
__global__ __launch_bounds__(256, 2) void k_gather(
    const int* __restrict__ qlc, const int* __restrict__ qrc,
    const int* __restrict__ slc, const int* __restrict__ srcn,
    const float* __restrict__ rel_mat, const float* __restrict__ ent_emb,
    const float* __restrict__ whh, const float* __restrict__ wih,
    float* __restrict__ ws)
{
    const int r    = blockIdx.x;
    const int tid  = threadIdx.x;
    const int wave = tid >> 6, lane = tid & 63;
    unsigned* stage_u = (unsigned*)(ws + OFF_STAGE);

    __shared__ int2 lst[CAP];
    __shared__ int  lcnt;
    if (tid == 0) lcnt = 0;

    // R row for this lane (4 redundant wave-copies; L2-resident)
    float Rr[64];
    {
        const float4* Rp = reinterpret_cast<const float4*>(rel_mat + (size_t)r * 4096 + lane * 64);
#pragma unroll
        for (int q = 0; q < 16; ++q) {
            const float4 v = Rp[q];
            Rr[4 * q + 0] = v.x; Rr[4 * q + 1] = v.y;
            Rr[4 * q + 2] = v.z; Rr[4 * q + 3] = v.w;
        }
    }
    __syncthreads();   // lcnt=0 visible

    // self-scan (no build kernel, no poison hazard)
    for (int e = tid; e < NEDGE; e += 256) {
        const int2* cp; int i;
        if (e < 25600)      { cp = (const int2*)qlc;  i = e; }
        else if (e < 51200) { cp = (const int2*)qrc;  i = e - 25600; }
        else if (e < 52200) { cp = (const int2*)slc;  i = e - 51200; }
        else                { cp = (const int2*)srcn; i = e - 52200; }
        const int2 ce = cp[i];   // {rel, ent}
        if (ce.x == r) {
            const int slot = atomicAdd(&lcnt, 1);
            if (slot < CAP) lst[slot] = make_int2(ce.y, e);
        }
    }
    __syncthreads();
    const int cnt = min(lcnt, CAP);

    for (int m = wave; m < cnt; m += 4) {
        const int2 ed = lst[m];
        const int ent = __builtin_amdgcn_readfirstlane(ed.x);
        const int e   = __builtin_amdgcn_readfirstlane(ed.y);
        const float4* ep = reinterpret_cast<const float4*>(ent_emb + (size_t)ent * 64);
        float a0 = 0.f, a1 = 0.f;
#pragma unroll
        for (int q = 0; q < 8; ++q) {
            const float4 e0 = ep[2 * q];
            const float4 e1 = ep[2 * q + 1];
            a0 = fmaf(Rr[8 * q + 0], e0.x, a0);
            a0 = fmaf(Rr[8 * q + 1], e0.y, a0);
            a0 = fmaf(Rr[8 * q + 2], e0.z, a0);
            a0 = fmaf(Rr[8 * q + 3], e0.w, a0);
            a1 = fmaf(Rr[8 * q + 4], e1.x, a1);
            a1 = fmaf(Rr[8 * q + 5], e1.y, a1);
            a1 = fmaf(Rr[8 * q + 6], e1.z, a1);
            a1 = fmaf(Rr[8 * q + 7], e1.w, a1);
        }
        const float acc = a0 + a1;
        const float par = __shfl_xor(acc, 1);
        if (!(lane & 1)) {   // even lane packs cols (lane, lane+1)
            stage_u[(size_t)e * 32 + (lane >> 1)] = bf16_rne(acc) | (bf16_rne(par) << 16);
        }
    }

    // lstm weight pack, spread over the grid (<=1 elem/thread)
    {
        const int idx = r * 256 + tid;
        if (idx < 98304) {
            unsigned* whhp = (unsigned*)(ws + OFF_WHHP);
            unsigned* wihp = (unsigned*)(ws + OFF_WIHP);
            if (idx < 65536) {                  // whh: 128 jp x 512 v
                const int v = idx & 511, jp = idx >> 9;
                const int u = ((v >> 7) << 8) + (v & 127);
                whhp[jp * 512 + v] = bf16_rne(whh[(2 * jp) * 1024 + u]) |
                                     (bf16_rne(whh[(2 * jp + 1) * 1024 + u]) << 16);
            } else {                            // wih: 64 jp x 512 v
                const int g2 = idx - 65536;
                const int v = g2 & 511, jp = g2 >> 9;
                const int u = ((v >> 7) << 8) + (v & 127);
                wihp[jp * 512 + v] = bf16_rne(wih[(2 * jp) * 1024 + u]) |
                                     (bf16_rne(wih[(2 * jp + 1) * 1024 + u]) << 16);
            }
        }
    }
}

// ---------------------------------------------------------------------------
// K2 k_post: 133 blocks x 256 (4 waves). Coalesced stage reduce: waves 0-1 =
// half L, waves 2-3 = half R; each wave-iter reads 2 full rows (256B
// contiguous). Then gcn projection -> MLP + residual + LayerNorm(ddof=1).
// ---------------------------------------------------------------------------
__global__ __launch_bounds__(256) void k_post(
    const float* __restrict__ gcn_w, const float* __restrict__ gcn_wb,
    const float* __restrict__ gcn_b,
    const float* __restrict__ qld, const float* __restrict__ qrd,
    const float* __restrict__ sld, const float* __restrict__ srd,
    const float* __restrict__ w1, const float* __restrict__ b1,
    const float* __restrict__ w2, const float* __restrict__ b2,
    const float* __restrict__ lng, const float* __restrict__ lnb,
    float* __restrict__ ws)
{
    const int blk = blockIdx.x, t = threadIdx.x;
    const unsigned* stage_u = (const unsigned*)(ws + OFF_STAGE);

    __shared__ float2 mmw[4][32];   // per-wave col-pair partials
    __shared__ float  mm[128];      // summed msg [L 64 | R 64]
    __shared__ float  degs[2];
    __shared__ float  x[128];
    __shared__ float  h1[256];
    __shared__ float  hh[128];
    __shared__ float  red[8];

    if (t < 2) {
        const float* dp;
        if (blk < 128) dp = t ? qrd + blk : qld + blk;
        else           dp = t ? srd + (blk - 128) : sld + (blk - 128);
        degs[t] = dp[0];
    }

    {   // coalesced reduce over 200 edge rows per half
        const int w = t >> 6, lane = t & 63;
        const int half = w >> 1, wl = w & 1;
        const int c = lane & 31, rp = lane >> 5;
        int e0;
        if (blk < 128) e0 = half ? 25600 + blk * 200 : blk * 200;
        else { const int f = blk - 128; e0 = half ? 52200 + f * 200 : 51200 + f * 200; }
        const unsigned* sp = stage_u + (size_t)e0 * 32 + (wl * 2 + rp) * 32 + c;
        float slo = 0.f, shi = 0.f;
#pragma unroll 10
        for (int it = 0; it < 50; ++it) {       // rows it*4 + wl*2 + rp
            const unsigned u = sp[it * 128];
            slo += __uint_as_float(u << 16);
            shi += __uint_as_float(u & 0xffff0000u);
        }
        slo += __shfl_xor(slo, 32);             // combine row-parity partner (same col)
        shi += __shfl_xor(shi, 32);
        if (rp == 0) mmw[w][c] = make_float2(slo, shi);
    }
    __syncthreads();
    if (t < 64) {
        const int half = t >> 5, c = t & 31;
        const float2 a = mmw[half * 2][c], b = mmw[half * 2 + 1][c];
        ((float2*)mm)[half * 32 + c] = make_float2(a.x + b.x, a.y + b.y);
    }
    __syncthreads();

    // projection
    if (t < 128) {
        const int col = t & 63, base = t & 64;
        float s = 0.f;
#pragma unroll 8
        for (int j = 0; j < 64; ++j) s = fmaf(mm[base + j], gcn_w[j * 64 + col], s);
        s += 200.f * (gcn_wb[col] + gcn_b[col]);
        x[t] = tanhf(s / degs[t >> 6]);
    }
    __syncthreads();

    // encoder
    {
        float s = b1[t];
#pragma unroll 8
        for (int j = 0; j < 128; ++j) s = fmaf(x[j], w1[j * 256 + t], s);
        h1[t] = fmaxf(s, 0.f);
    }
    __syncthreads();
    if (t < 128) {
        float s = b2[t] + x[t];
#pragma unroll 8
        for (int k = 0; k < 256; ++k) s = fmaf(h1[k], w2[k * 128 + t], s);
        hh[t] = s;
    }
    __syncthreads();

    // LayerNorm ddof=1
    float v = (t < 128) ? hh[t] : 0.f;
#pragma unroll
    for (int m = 32; m >= 1; m >>= 1) v += __shfl_xor(v, m);
    if ((t & 63) == 0) red[t >> 6] = v;
    __syncthreads();
    const float mu = (red[0] + red[1]) * (1.f / 128.f);
    float d = (t < 128) ? (hh[t] - mu) : 0.f;
    float v2 = d * d;
#pragma unroll
    for (int m = 32; m >= 1; m >>= 1) v2 += __shfl_xor(v2, m);
    if ((t & 63) == 0) red[4 + (t >> 6)] = v2;
    __syncthreads();
    const float var = (red[4] + red[5]) * (1.f / 127.f);
    const float rs = 1.f / (sqrtf(var) + 0.001f);
    if (t < 128) {
        float* xout = (blk < 128) ? ws + OFF_QG + blk * 128 : ws + OFF_SG + (blk - 128) * 128;
        xout[t] = (hh[t] - mu) * rs * lng[t] + lnb[t];
    }
}

// ---------------------------------------------------------------------------
// K3 k_lstm: 128 blocks x 512 (one batch row per block). Thread t owns live
// gate unit t (cells 0..127 x {i,f,g,o}); dead cells 128..255 of h_r_ are
// never read by the reference. Four independent fma chains.
// ---------------------------------------------------------------------------
__global__ __launch_bounds__(512) void k_lstm(
    const float* __restrict__ bih, const float* __restrict__ bhh,
    float* __restrict__ ws, float* __restrict__ outp)
{
    const int t = threadIdx.x;
    const int b = blockIdx.x;
    const unsigned* whhp = (const unsigned*)(ws + OFF_WHHP);
    const unsigned* wihp = (const unsigned*)(ws + OFF_WIHP);

    __shared__ float sgf[5 * 128];
    __shared__ float qg[128];
    __shared__ float hr[256];     // h | r
    __shared__ float gbuf[512];
    __shared__ float redw[2][5];

    for (int i = t; i < 640; i += 512) sgf[i] = (ws + OFF_SG)[i];
    if (t < 128) qg[t] = (ws + OFF_QG)[(size_t)b * 128 + t];
    if (t < 256) hr[t] = 0.f;

    const int u = ((t >> 7) << 8) + (t & 127);
    float xp = bih[u] + bhh[u];
    __syncthreads();

    const float2* qg2 = (const float2*)qg;
    const float2* hr2 = (const float2*)hr;

#pragma unroll 8
    for (int jp = 0; jp < 64; ++jp) {
        const unsigned w = wihp[jp * 512 + t];
        const float2 q = qg2[jp];
        xp = fmaf(__uint_as_float(w << 16), q.x,
             fmaf(__uint_as_float(w & 0xffff0000u), q.y, xp));
    }

    float c = 0.f;
    const int tp = t & 127;

    for (int step = 0; step < 4; ++step) {
        float g0 = xp, g1 = 0.f, g2 = 0.f, g3 = 0.f;
#pragma unroll 4
        for (int jp = 0; jp < 128; jp += 4) {
            const unsigned w0 = whhp[(jp + 0) * 512 + t];
            const unsigned w1 = whhp[(jp + 1) * 512 + t];
            const unsigned w2 = whhp[(jp + 2) * 512 + t];
            const unsigned w3 = whhp[(jp + 3) * 512 + t];
            const float2 h0 = hr2[jp + 0], h1 = hr2[jp + 1];
            const float2 h2 = hr2[jp + 2], h3 = hr2[jp + 3];
            g0 = fmaf(__uint_as_float(w0 << 16), h0.x, fmaf(__uint_as_float(w0 & 0xffff0000u), h0.y, g0));
            g1 = fmaf(__uint_as_float(w1 << 16), h1.x, fmaf(__uint_as_float(w1 & 0xffff0000u), h1.y, g1));
            g2 = fmaf(__uint_as_float(w2 << 16), h2.x, fmaf(__uint_as_float(w2 & 0xffff0000u), h2.y, g2));
            g3 = fmaf(__uint_as_float(w3 << 16), h3.x, fmaf(__uint_as_float(w3 & 0xffff0000u), h3.y, g3));
        }
        gbuf[t] = (g0 + g1) + (g2 + g3);
        __syncthreads();   // gates ready; hr reads done

        float hv = 0.f;
        if (t < 128) {
            const float iv = sigm(gbuf[tp]);
            const float fv = sigm(gbuf[128 + tp]);
            const float gv = tanhf(gbuf[256 + tp]);
            const float ov = sigm(gbuf[384 + tp]);
            c = fv * c + iv * gv;
            hv = qg[tp] + ov * tanhf(c);
            hr[tp] = hv;
        }

        float p0 = 0, p1 = 0, p2 = 0, p3 = 0, p4 = 0;
        if (t < 128) {
            p0 = hv * sgf[0 * 128 + tp];
            p1 = hv * sgf[1 * 128 + tp];
            p2 = hv * sgf[2 * 128 + tp];
            p3 = hv * sgf[3 * 128 + tp];
            p4 = hv * sgf[4 * 128 + tp];
#pragma unroll
            for (int m = 32; m >= 1; m >>= 1) {
                p0 += __shfl_xor(p0, m);
                p1 += __shfl_xor(p1, m);
                p2 += __shfl_xor(p2, m);
                p3 += __shfl_xor(p3, m);
                p4 += __shfl_xor(p4, m);
            }
            if ((t & 63) == 0) {
                const int w = t >> 6;
                redw[w][0] = p0; redw[w][1] = p1; redw[w][2] = p2;
                redw[w][3] = p3; redw[w][4] = p4;
            }
        }
        __syncthreads();

        const float d0 = redw[0][0] + redw[1][0];
        const float d1 = redw[0][1] + redw[1][1];
        const float d2 = redw[0][2] + redw[1][2];
        const float d3 = redw[0][3] + redw[1][3];
        const float d4 = redw[0][4] + redw[1][4];

        if (step == 3) {
            if (t == 0) {
                float* o = outp + (size_t)b * 5;
                o[0] = d0; o[1] = d1; o[2] = d2; o[3] = d3; o[4] = d4;
            }
        }
        if (t < 128) {
            const float mx = fmaxf(fmaxf(fmaxf(d0, d1), fmaxf(d2, d3)), d4);
            const float e0 = __expf(d0 - mx), e1 = __expf(d1 - mx), e2 = __expf(d2 - mx),
                        e3 = __expf(d3 - mx), e4 = __expf(d4 - mx);
            const float inv = 1.f / (e0 + e1 + e2 + e3 + e4);
            hr[128 + tp] = (e0 * sgf[0 * 128 + tp] + e1 * sgf[1 * 128 + tp] +
                            e2 * sgf[2 * 128 + tp] + e3 * sgf[3 * 128 + tp] +
                            e4 * sgf[4 * 128 + tp]) * inv;
        }
        __syncthreads();
    }
}

// ---------------------------------------------------------------------------
extern "C" void kernel_launch(void* const* d_in, const int* in_sizes, int n_in,
                              void* d_out, int out_size, void* d_ws, size_t ws_size,
                              hipStream_t stream) {
    const int*   qlc = (const int*)d_in[0];
    const int*   qrc = (const int*)d_in[1];
    const int*   slc = (const int*)d_in[2];
    const int*   srcn= (const int*)d_in[3];
    const float* qld = (const float*)d_in[4];
    const float* qrd = (const float*)d_in[5];
    const float* sld = (const float*)d_in[6];
    const float* srd = (const float*)d_in[7];
    const float* ent = (const float*)d_in[8];
    const float* rel = (const float*)d_in[9];
    const float* gw  = (const float*)d_in[10];
    const float* gwb = (const float*)d_in[11];
    const float* gb  = (const float*)d_in[12];
    const float* w1  = (const float*)d_in[13];
    const float* b1  = (const float*)d_in[14];
    const float* w2  = (const float*)d_in[15];
    const float* b2  = (const float*)d_in[16];
    const float* lng = (const float*)d_in[17];
    const float* lnb = (const float*)d_in[18];
    const float* wih = (const float*)d_in[19];
    const float* whh = (const float*)d_in[20];
    const float* bih = (const float*)d_in[21];
    const float* bhh = (const float*)d_in[22];

    float* ws   = (float*)d_ws;
    float* outp = (float*)d_out;

    hipLaunchKernelGGL(k_gather, dim3(NREL), dim3(256), 0, stream,
                       qlc, qrc, slc, srcn, rel, ent, whh, wih, ws);
    hipLaunchKernelGGL(k_post,   dim3(133), dim3(256), 0, stream,
                       gw, gwb, gb, qld, qrd, sld, srd,
                       w1, b1, w2, b2, lng, lnb, ws);
    hipLaunchKernelGGL(k_lstm,   dim3(128), dim3(512), 0, stream, bih, bhh, ws, outp);
}

// Round 8
// 190.406 us; speedup vs baseline: 1.2615x; 1.2615x over previous
//
#include <hip/hip_runtime.h>
#include <math.h>

#define NREL 500
#define CAP  256
#define NEDGE 53200   // qlc [0,25600) qrc [25600,51200) slc [51200,52200) srcn [52200,53200)

__device__ __forceinline__ float sigm(float x) { return 1.0f / (1.0f + __expf(-x)); }
__device__ __forceinline__ unsigned bf16_rne(float x) {
    unsigned b = __float_as_uint(x);
    return (b + 0x7fffu + ((b >> 16) & 1u)) >> 16;
}
__device__ __forceinline__ float bflo(unsigned u) { return __uint_as_float(u << 16); }
__device__ __forceinline__ float bfhi(unsigned u) { return __uint_as_float(u & 0xffff0000u); }

// ws layout (float offsets), total 3,098,240 floats = 12.4 MiB (R5 proved >=14.2 MiB available)
#define OFF_COUNTS 0              // 512 uints (atomic targets; NEVER zeroed — poison-tolerant)
#define OFF_LIST   512            // 500*256 int2
#define OFF_WHHP   256512         // 128*512 uint (bf16 pairs, live cols)
#define OFF_WIHP   322048         // 64*512 uint
#define OFF_QG     354816         // 128*128
#define OFF_SG     371200         // 5*128
#define OFF_RELP   371840         // 500*2048 uint: rel_mat rows as bf16 pairs
#define OFF_STAGE  1395840        // 53200*32 uint (bf16 pairs per edge row)

// ---------------------------------------------------------------------------
// K1 k_prep: (a) scatter 53200 edges into per-rel tagged lists (counts start
// at POISON — slot = ret % CAP is consecutive per rel regardless of base;
// entries carry tag 0x5 + field validation so poison slots are rejected);
// (b) pack live lstm weight cols to bf16 pairs; (c) pack rel_mat to bf16
// pairs. 2297 blocks x 512.
// ---------------------------------------------------------------------------
__global__ __launch_bounds__(512) void k_prep(
    const int* __restrict__ qlc, const int* __restrict__ qrc,
    const int* __restrict__ slc, const int* __restrict__ srcn,
    const float* __restrict__ rel_mat,
    const float* __restrict__ whh, const float* __restrict__ wih,
    float* __restrict__ ws)
{
    const int idx = blockIdx.x * 512 + threadIdx.x;
    if (idx < NEDGE) {
        unsigned* counts = (unsigned*)(ws + OFF_COUNTS);
        int2* list2 = (int2*)(ws + OFF_LIST);
        const int e = idx;
        const int* cp; int i, dest;
        if (e < 25600)      { cp = qlc;  i = e;         dest = i / 200; }
        else if (e < 51200) { cp = qrc;  i = e - 25600; dest = 128 + i / 200; }
        else if (e < 52200) { cp = slc;  i = e - 51200; dest = 256 + i / 200; }
        else                { cp = srcn; i = e - 52200; dest = 261 + i / 200; }
        const int rel = cp[2 * i];
        const int ent = cp[2 * i + 1];
        const unsigned ret = atomicAdd(&counts[rel], 1u);
        const int slot = (int)(ret & (CAP - 1));
        const int meta = 0x50000000 | (e << 9) | dest;
        list2[rel * CAP + slot] = make_int2(ent, meta);
    } else if (idx < NEDGE + 98304) {
        unsigned* whhp = (unsigned*)(ws + OFF_WHHP);
        unsigned* wihp = (unsigned*)(ws + OFF_WIHP);
        const int p = idx - NEDGE;
        if (p < 65536) {                    // whh: 128 jp x 512 v
            const int v = p & 511, jp = p >> 9;
            const int u = ((v >> 7) << 8) + (v & 127);
            whhp[jp * 512 + v] = bf16_rne(whh[(2 * jp) * 1024 + u]) |
                                 (bf16_rne(whh[(2 * jp + 1) * 1024 + u]) << 16);
        } else {                            // wih: 64 jp x 512 v
            const int g2 = p - 65536;
            const int v = g2 & 511, jp = g2 >> 9;
            const int u = ((v >> 7) << 8) + (v & 127);
            wihp[jp * 512 + v] = bf16_rne(wih[(2 * jp) * 1024 + u]) |
                                 (bf16_rne(wih[(2 * jp + 1) * 1024 + u]) << 16);
        }
    } else if (idx < NEDGE + 98304 + 1024000) {
        const int p = idx - (NEDGE + 98304);    // uint index into relp
        unsigned* relp = (unsigned*)(ws + OFF_RELP);
        relp[p] = bf16_rne(rel_mat[2 * p]) | (bf16_rne(rel_mat[2 * p + 1]) << 16);
    }
}

// ---------------------------------------------------------------------------
// K2 k_gather: 500 blocks x 256 threads (4 waves). R[r] staged in LDS as bf16
// pairs, padded pitch 34 uints/row -> per-edge inner loop is just 16
// ds_read_b64 (2-way bank alias = free) + 64 unpack + 64 fma. e-vector loads
// are wave-uniform (readfirstlane -> scalar path). NO per-lane register
// array (R5/R7 lesson: 64-deep arrays spill regardless of launch_bounds).
// Stage rows written exactly once as bf16 pairs (no atomics, no zero-init).
// ---------------------------------------------------------------------------
__global__ __launch_bounds__(256) void k_gather(
    const float* __restrict__ ent_emb, float* __restrict__ ws)
{
    const int r    = blockIdx.x;
    const int tid  = threadIdx.x;
    const int wave = tid >> 6, lane = tid & 63;
    unsigned* stage_u = (unsigned*)(ws + OFF_STAGE);

    __shared__ unsigned Rl[64 * 34];   // row i at i*34, cols as bf16 pairs
    __shared__ int2 lst[CAP];
    __shared__ int  lcnt;
    if (tid == 0) lcnt = 0;

    {   // stage R[r]: 2048 uints, conflict-free writes
        const unsigned* rp = (const unsigned*)(ws + OFF_RELP) + r * 2048;
        for (int g = tid; g < 2048; g += 256)
            Rl[(g >> 5) * 34 + (g & 31)] = rp[g];
    }

    {   // compact valid tagged entries (rejects poison)
        const int2* list2 = (const int2*)(ws + OFF_LIST) + r * CAP;
        const int2 en = list2[tid];
        const int meta = en.y;
        const int e = (meta >> 9) & 0xffff, dest = meta & 511;
        const bool ok = ((meta >> 28) & 0xf) == 0x5 && e < NEDGE && dest < 266 &&
                        en.x >= 0 && en.x < 501;
        __syncthreads();   // Rl staged, lcnt=0 visible
        if (ok) {
            const int s = atomicAdd(&lcnt, 1);
            lst[s] = en;
        }
    }
    __syncthreads();
    const int cnt = lcnt;

    const unsigned* rl = &Rl[lane * 34];
    for (int m = wave; m < cnt; m += 4) {
        const int2 ed = lst[m];
        const int ent = __builtin_amdgcn_readfirstlane(ed.x);
        const int e   = __builtin_amdgcn_readfirstlane((ed.y >> 9) & 0xffff);
        const float4* ep = reinterpret_cast<const float4*>(ent_emb + (size_t)ent * 64);
        float a0 = 0.f, a1 = 0.f;
#pragma unroll
        for (int q = 0; q < 16; q += 2) {
            const uint2 rp0 = *reinterpret_cast<const uint2*>(&rl[2 * q]);
            const uint2 rp1 = *reinterpret_cast<const uint2*>(&rl[2 * q + 2]);
            const float4 e0 = ep[q];
            const float4 e1 = ep[q + 1];
            a0 = fmaf(bflo(rp0.x), e0.x, a0);
            a0 = fmaf(bfhi(rp0.x), e0.y, a0);
            a0 = fmaf(bflo(rp0.y), e0.z, a0);
            a0 = fmaf(bfhi(rp0.y), e0.w, a0);
            a1 = fmaf(bflo(rp1.x), e1.x, a1);
            a1 = fmaf(bfhi(rp1.x), e1.y, a1);
            a1 = fmaf(bflo(rp1.y), e1.z, a1);
            a1 = fmaf(bfhi(rp1.y), e1.w, a1);
        }
        const float acc = a0 + a1;
        const float par = __shfl_xor(acc, 1);
        if (!(lane & 1)) {   // even lane packs cols (lane, lane+1)
            stage_u[(size_t)e * 32 + (lane >> 1)] = bf16_rne(acc) | (bf16_rne(par) << 16);
        }
    }
}

// ---------------------------------------------------------------------------
// K3 k_post: 133 blocks x 256 (4 waves). Coalesced stage reduce (waves 0-1 =
// half L, 2-3 = half R; each wave-iter reads 2 full rows = 256B contiguous),
// then gcn projection -> MLP + residual + LayerNorm(ddof=1) -> QG/SG.
// ---------------------------------------------------------------------------
__global__ __launch_bounds__(256) void k_post(
    const float* __restrict__ gcn_w, const float* __restrict__ gcn_wb,
    const float* __restrict__ gcn_b,
    const float* __restrict__ qld, const float* __restrict__ qrd,
    const float* __restrict__ sld, const float* __restrict__ srd,
    const float* __restrict__ w1, const float* __restrict__ b1,
    const float* __restrict__ w2, const float* __restrict__ b2,
    const float* __restrict__ lng, const float* __restrict__ lnb,
    float* __restrict__ ws)
{
    const int blk = blockIdx.x, t = threadIdx.x;
    const unsigned* stage_u = (const unsigned*)(ws + OFF_STAGE);

    __shared__ float2 mmw[4][32];
    __shared__ float  mm[128];
    __shared__ float  degs[2];
    __shared__ float  x[128];
    __shared__ float  h1[256];
    __shared__ float  hh[128];
    __shared__ float  red[8];

    if (t < 2) {
        const float* dp;
        if (blk < 128) dp = t ? qrd + blk : qld + blk;
        else           dp = t ? srd + (blk - 128) : sld + (blk - 128);
        degs[t] = dp[0];
    }

    {   // coalesced reduce over 200 edge rows per half
        const int w = t >> 6, lane = t & 63;
        const int half = w >> 1, wl = w & 1;
        const int c = lane & 31, rp = lane >> 5;
        int e0;
        if (blk < 128) e0 = half ? 25600 + blk * 200 : blk * 200;
        else { const int f = blk - 128; e0 = half ? 52200 + f * 200 : 51200 + f * 200; }
        const unsigned* sp = stage_u + (size_t)e0 * 32 + (wl * 2 + rp) * 32 + c;
        float slo = 0.f, shi = 0.f;
#pragma unroll 10
        for (int it = 0; it < 50; ++it) {
            const unsigned u = sp[it * 128];
            slo += bflo(u);
            shi += bfhi(u);
        }
        slo += __shfl_xor(slo, 32);
        shi += __shfl_xor(shi, 32);
        if (rp == 0) mmw[w][c] = make_float2(slo, shi);
    }
    __syncthreads();
    if (t < 64) {
        const int half = t >> 5, c = t & 31;
        const float2 a = mmw[half * 2][c], b = mmw[half * 2 + 1][c];
        ((float2*)mm)[half * 32 + c] = make_float2(a.x + b.x, a.y + b.y);
    }
    __syncthreads();

    if (t < 128) {
        const int col = t & 63, base = t & 64;
        float s = 0.f;
#pragma unroll 8
        for (int j = 0; j < 64; ++j) s = fmaf(mm[base + j], gcn_w[j * 64 + col], s);
        s += 200.f * (gcn_wb[col] + gcn_b[col]);
        x[t] = tanhf(s / degs[t >> 6]);
    }
    __syncthreads();

    {
        float s = b1[t];
#pragma unroll 8
        for (int j = 0; j < 128; ++j) s = fmaf(x[j], w1[j * 256 + t], s);
        h1[t] = fmaxf(s, 0.f);
    }
    __syncthreads();
    if (t < 128) {
        float s = b2[t] + x[t];
#pragma unroll 8
        for (int k = 0; k < 256; ++k) s = fmaf(h1[k], w2[k * 128 + t], s);
        hh[t] = s;
    }
    __syncthreads();

    float v = (t < 128) ? hh[t] : 0.f;
#pragma unroll
    for (int m = 32; m >= 1; m >>= 1) v += __shfl_xor(v, m);
    if ((t & 63) == 0) red[t >> 6] = v;
    __syncthreads();
    const float mu = (red[0] + red[1]) * (1.f / 128.f);
    float d = (t < 128) ? (hh[t] - mu) : 0.f;
    float v2 = d * d;
#pragma unroll
    for (int m = 32; m >= 1; m >>= 1) v2 += __shfl_xor(v2, m);
    if ((t & 63) == 0) red[4 + (t >> 6)] = v2;
    __syncthreads();
    const float var = (red[4] + red[5]) * (1.f / 127.f);
    const float rs = 1.f / (sqrtf(var) + 0.001f);
    if (t < 128) {
        float* xout = (blk < 128) ? ws + OFF_QG + blk * 128 : ws + OFF_SG + (blk - 128) * 128;
        xout[t] = (hh[t] - mu) * rs * lng[t] + lnb[t];
    }
}

// ---------------------------------------------------------------------------
// K4 k_lstm: 128 blocks x 512 (one batch row per block). Thread t owns live
// gate unit t (cells 0..127 x {i,f,g,o}); h_r_[:,128:256] is dead in the
// reference. Four independent fma chains over bf16-packed weights.
// ---------------------------------------------------------------------------
__global__ __launch_bounds__(512) void k_lstm(
    const float* __restrict__ bih, const float* __restrict__ bhh,
    float* __restrict__ ws, float* __restrict__ outp)
{
    const int t = threadIdx.x;
    const int b = blockIdx.x;
    const unsigned* whhp = (const unsigned*)(ws + OFF_WHHP);
    const unsigned* wihp = (const unsigned*)(ws + OFF_WIHP);

    __shared__ float sgf[5 * 128];
    __shared__ float qg[128];
    __shared__ float hr[256];
    __shared__ float gbuf[512];
    __shared__ float redw[2][5];

    for (int i = t; i < 640; i += 512) sgf[i] = (ws + OFF_SG)[i];
    if (t < 128) qg[t] = (ws + OFF_QG)[(size_t)b * 128 + t];
    if (t < 256) hr[t] = 0.f;

    const int u = ((t >> 7) << 8) + (t & 127);
    float xp = bih[u] + bhh[u];
    __syncthreads();

    const float2* qg2 = (const float2*)qg;
    const float2* hr2 = (const float2*)hr;

#pragma unroll 8
    for (int jp = 0; jp < 64; ++jp) {
        const unsigned w = wihp[jp * 512 + t];
        const float2 q = qg2[jp];
        xp = fmaf(bflo(w), q.x, fmaf(bfhi(w), q.y, xp));
    }

    float c = 0.f;
    const int tp = t & 127;

    for (int step = 0; step < 4; ++step) {
        float g0 = xp, g1 = 0.f, g2 = 0.f, g3 = 0.f;
#pragma unroll 4
        for (int jp = 0; jp < 128; jp += 4) {
            const unsigned w0 = whhp[(jp + 0) * 512 + t];
            const unsigned w1 = whhp[(jp + 1) * 512 + t];
            const unsigned w2 = whhp[(jp + 2) * 512 + t];
            const unsigned w3 = whhp[(jp + 3) * 512 + t];
            const float2 h0 = hr2[jp + 0], h1 = hr2[jp + 1];
            const float2 h2 = hr2[jp + 2], h3 = hr2[jp + 3];
            g0 = fmaf(bflo(w0), h0.x, fmaf(bfhi(w0), h0.y, g0));
            g1 = fmaf(bflo(w1), h1.x, fmaf(bfhi(w1), h1.y, g1));
            g2 = fmaf(bflo(w2), h2.x, fmaf(bfhi(w2), h2.y, g2));
            g3 = fmaf(bflo(w3), h3.x, fmaf(bfhi(w3), h3.y, g3));
        }
        gbuf[t] = (g0 + g1) + (g2 + g3);
        __syncthreads();

        float hv = 0.f;
        if (t < 128) {
            const float iv = sigm(gbuf[tp]);
            const float fv = sigm(gbuf[128 + tp]);
            const float gv = tanhf(gbuf[256 + tp]);
            const float ov = sigm(gbuf[384 + tp]);
            c = fv * c + iv * gv;
            hv = qg[tp] + ov * tanhf(c);
            hr[tp] = hv;
        }

        float p0 = 0, p1 = 0, p2 = 0, p3 = 0, p4 = 0;
        if (t < 128) {
            p0 = hv * sgf[0 * 128 + tp];
            p1 = hv * sgf[1 * 128 + tp];
            p2 = hv * sgf[2 * 128 + tp];
            p3 = hv * sgf[3 * 128 + tp];
            p4 = hv * sgf[4 * 128 + tp];
#pragma unroll
            for (int m = 32; m >= 1; m >>= 1) {
                p0 += __shfl_xor(p0, m);
                p1 += __shfl_xor(p1, m);
                p2 += __shfl_xor(p2, m);
                p3 += __shfl_xor(p3, m);
                p4 += __shfl_xor(p4, m);
            }
            if ((t & 63) == 0) {
                const int w = t >> 6;
                redw[w][0] = p0; redw[w][1] = p1; redw[w][2] = p2;
                redw[w][3] = p3; redw[w][4] = p4;
            }
        }
        __syncthreads();

        const float d0 = redw[0][0] + redw[1][0];
        const float d1 = redw[0][1] + redw[1][1];
        const float d2 = redw[0][2] + redw[1][2];
        const float d3 = redw[0][3] + redw[1][3];
        const float d4 = redw[0][4] + redw[1][4];

        if (step == 3) {
            if (t == 0) {
                float* o = outp + (size_t)b * 5;
                o[0] = d0; o[1] = d1; o[2] = d2; o[3] = d3; o[4] = d4;
            }
        }
        if (t < 128) {
            const float mx = fmaxf(fmaxf(fmaxf(d0, d1), fmaxf(d2, d3)), d4);
            const float e0 = __expf(d0 - mx), e1 = __expf(d1 - mx), e2 = __expf(d2 - mx),
                        e3 = __expf(d3 - mx), e4 = __expf(d4 - mx);
            const float inv = 1.f / (e0 + e1 + e2 + e3 + e4);
            hr[128 + tp] = (e0 * sgf[0 * 128 + tp] + e1 * sgf[1 * 128 + tp] +
                            e2 * sgf[2 * 128 + tp] + e3 * sgf[3 * 128 + tp] +
                            e4 * sgf[4 * 128 + tp]) * inv;
        }
        __syncthreads();
    }
}

// ---------------------------------------------------------------------------
extern "C" void kernel_launch(void* const* d_in, const int* in_sizes, int n_in,
                              void* d_out, int out_size, void* d_ws, size_t ws_size,
                              hipStream_t stream) {
    const int*   qlc = (const int*)d_in[0];
    const int*   qrc = (const int*)d_in[1];
    const int*   slc = (const int*)d_in[2];
    const int*   srcn= (const int*)d_in[3];
    const float* qld = (const float*)d_in[4];
    const float* qrd = (const float*)d_in[5];
    const float* sld = (const float*)d_in[6];
    const float* srd = (const float*)d_in[7];
    const float* ent = (const float*)d_in[8];
    const float* rel = (const float*)d_in[9];
    const float* gw  = (const float*)d_in[10];
    const float* gwb = (const float*)d_in[11];
    const float* gb  = (const float*)d_in[12];
    const float* w1  = (const float*)d_in[13];
    const float* b1  = (const float*)d_in[14];
    const float* w2  = (const float*)d_in[15];
    const float* b2  = (const float*)d_in[16];
    const float* lng = (const float*)d_in[17];
    const float* lnb = (const float*)d_in[18];
    const float* wih = (const float*)d_in[19];
    const float* whh = (const float*)d_in[20];
    const float* bih = (const float*)d_in[21];
    const float* bhh = (const float*)d_in[22];

    float* ws   = (float*)d_ws;
    float* outp = (float*)d_out;

    hipLaunchKernelGGL(k_prep,   dim3(2297), dim3(512), 0, stream,
                       qlc, qrc, slc, srcn, rel, whh, wih, ws);
    hipLaunchKernelGGL(k_gather, dim3(NREL), dim3(256), 0, stream, ent, ws);
    hipLaunchKernelGGL(k_post,   dim3(133), dim3(256), 0, stream,
                       gw, gwb, gb, qld, qrd, sld, srd,
                       w1, b1, w2, b2, lng, lnb, ws);
    hipLaunchKernelGGL(k_lstm,   dim3(128), dim3(512), 0, stream, bih, bhh, ws, outp);
}

// Round 9
// 186.963 us; speedup vs baseline: 1.2847x; 1.0184x over previous
//
#include <hip/hip_runtime.h>
#include <math.h>

#define NREL 500
#define CAP  256
#define NEDGE 53200   // qlc [0,25600) qrc [25600,51200) slc [51200,52200) srcn [52200,53200)

__device__ __forceinline__ float sigm(float x) { return 1.0f / (1.0f + __expf(-x)); }
__device__ __forceinline__ unsigned bf16_rne(float x) {
    unsigned b = __float_as_uint(x);
    return (b + 0x7fffu + ((b >> 16) & 1u)) >> 16;
}
__device__ __forceinline__ float bflo(unsigned u) { return __uint_as_float(u << 16); }
__device__ __forceinline__ float bfhi(unsigned u) { return __uint_as_float(u & 0xffff0000u); }

// ws layout (float offsets), total 2,074,240 floats = 8.3 MiB (proven safe)
#define OFF_COUNTS 0              // 512 uints (atomic targets; NEVER zeroed — poison-tolerant)
#define OFF_LIST   512            // 500*256 int2
#define OFF_WHHP   256512         // 128*512 uint (bf16 pairs, live cols)
#define OFF_WIHP   322048         // 64*512 uint
#define OFF_QG     354816         // 128*128
#define OFF_SG     371200         // 5*128
#define OFF_STAGE  371840         // 53200*32 uint (bf16 pairs per edge row)

// ---------------------------------------------------------------------------
// K1 k_prep: (a) scatter 53200 edges into per-rel tagged lists (counts start
// at POISON — slot = ret % CAP is consecutive per rel regardless of base;
// entries carry tag 0x5 + field validation so poison slots are rejected);
// (b) pack live lstm weight cols to bf16 pairs. 296 blocks x 512.
// ---------------------------------------------------------------------------
__global__ __launch_bounds__(512) void k_prep(
    const int* __restrict__ qlc, const int* __restrict__ qrc,
    const int* __restrict__ slc, const int* __restrict__ srcn,
    const float* __restrict__ whh, const float* __restrict__ wih,
    float* __restrict__ ws)
{
    const int idx = blockIdx.x * 512 + threadIdx.x;
    if (idx < NEDGE) {
        unsigned* counts = (unsigned*)(ws + OFF_COUNTS);
        int2* list2 = (int2*)(ws + OFF_LIST);
        const int e = idx;
        const int* cp; int i, dest;
        if (e < 25600)      { cp = qlc;  i = e;         dest = i / 200; }
        else if (e < 51200) { cp = qrc;  i = e - 25600; dest = 128 + i / 200; }
        else if (e < 52200) { cp = slc;  i = e - 51200; dest = 256 + i / 200; }
        else                { cp = srcn; i = e - 52200; dest = 261 + i / 200; }
        const int rel = cp[2 * i];
        const int ent = cp[2 * i + 1];
        const unsigned ret = atomicAdd(&counts[rel], 1u);
        const int slot = (int)(ret & (CAP - 1));
        const int meta = 0x50000000 | (e << 9) | dest;
        list2[rel * CAP + slot] = make_int2(ent, meta);
    } else if (idx < NEDGE + 98304) {
        unsigned* whhp = (unsigned*)(ws + OFF_WHHP);
        unsigned* wihp = (unsigned*)(ws + OFF_WIHP);
        const int p = idx - NEDGE;
        if (p < 65536) {                    // whh: 128 jp x 512 v
            const int v = p & 511, jp = p >> 9;
            const int u = ((v >> 7) << 8) + (v & 127);
            whhp[jp * 512 + v] = bf16_rne(whh[(2 * jp) * 1024 + u]) |
                                 (bf16_rne(whh[(2 * jp + 1) * 1024 + u]) << 16);
        } else {                            // wih: 64 jp x 512 v
            const int g2 = p - 65536;
            const int v = g2 & 511, jp = g2 >> 9;
            const int u = ((v >> 7) << 8) + (v & 127);
            wihp[jp * 512 + v] = bf16_rne(wih[(2 * jp) * 1024 + u]) |
                                 (bf16_rne(wih[(2 * jp + 1) * 1024 + u]) << 16);
        }
    }
}

// ---------------------------------------------------------------------------
// K2 k_gather: 500 blocks x 512 threads (8 waves). R[r] converted f32->bf16
// on the fly while staging into LDS (padded pitch 34 uints/row). Per edge:
// 16 ds_read_b64 (2-way bank alias = free) + 64 unpack + 64 fma; e-vector
// loads wave-uniform (readfirstlane -> scalar path). NO per-lane register
// array (R5/R7 lesson: 64-deep arrays spill regardless of launch_bounds).
// Stage rows written exactly once as bf16 pairs (no atomics, no zero-init).
// ---------------------------------------------------------------------------
__global__ __launch_bounds__(512) void k_gather(
    const float* __restrict__ rel_mat, const float* __restrict__ ent_emb,
    float* __restrict__ ws)
{
    const int r    = blockIdx.x;
    const int tid  = threadIdx.x;
    const int wave = tid >> 6, lane = tid & 63;
    unsigned* stage_u = (unsigned*)(ws + OFF_STAGE);

    __shared__ unsigned Rl[64 * 34];   // row i at i*34, cols as bf16 pairs
    __shared__ int2 lst[CAP];
    __shared__ int  lcnt;
    if (tid == 0) lcnt = 0;

    {   // stage R[r] with on-the-fly f32->bf16 pair pack (4 float2 loads/thread)
        const float2* rp = reinterpret_cast<const float2*>(rel_mat + (size_t)r * 4096);
        for (int g = tid; g < 2048; g += 512) {
            const float2 v = rp[g];
            Rl[(g >> 5) * 34 + (g & 31)] = bf16_rne(v.x) | (bf16_rne(v.y) << 16);
        }
    }

    // compact valid tagged entries (rejects poison)
    int2 en = make_int2(0, 0);
    bool ok = false;
    if (tid < CAP) {
        const int2* list2 = (const int2*)(ws + OFF_LIST) + r * CAP;
        en = list2[tid];
        const int meta = en.y;
        const int e = (meta >> 9) & 0xffff, dest = meta & 511;
        ok = ((meta >> 28) & 0xf) == 0x5 && e < NEDGE && dest < 266 &&
             en.x >= 0 && en.x < 501;
    }
    __syncthreads();   // Rl staged, lcnt=0 visible
    if (ok) {
        const int s = atomicAdd(&lcnt, 1);
        lst[s] = en;
    }
    __syncthreads();
    const int cnt = lcnt;

    const unsigned* rl = &Rl[lane * 34];
    for (int m = wave; m < cnt; m += 8) {
        const int2 ed = lst[m];
        const int ent = __builtin_amdgcn_readfirstlane(ed.x);
        const int e   = __builtin_amdgcn_readfirstlane((ed.y >> 9) & 0xffff);
        const float4* ep = reinterpret_cast<const float4*>(ent_emb + (size_t)ent * 64);
        float a0 = 0.f, a1 = 0.f;
#pragma unroll
        for (int q = 0; q < 16; q += 2) {
            const uint2 rp0 = *reinterpret_cast<const uint2*>(&rl[2 * q]);
            const uint2 rp1 = *reinterpret_cast<const uint2*>(&rl[2 * q + 2]);
            const float4 e0 = ep[q];
            const float4 e1 = ep[q + 1];
            a0 = fmaf(bflo(rp0.x), e0.x, a0);
            a0 = fmaf(bfhi(rp0.x), e0.y, a0);
            a0 = fmaf(bflo(rp0.y), e0.z, a0);
            a0 = fmaf(bfhi(rp0.y), e0.w, a0);
            a1 = fmaf(bflo(rp1.x), e1.x, a1);
            a1 = fmaf(bfhi(rp1.x), e1.y, a1);
            a1 = fmaf(bflo(rp1.y), e1.z, a1);
            a1 = fmaf(bfhi(rp1.y), e1.w, a1);
        }
        const float acc = a0 + a1;
        const float par = __shfl_xor(acc, 1);
        if (!(lane & 1)) {   // even lane packs cols (lane, lane+1)
            stage_u[(size_t)e * 32 + (lane >> 1)] = bf16_rne(acc) | (bf16_rne(par) << 16);
        }
    }
}

// ---------------------------------------------------------------------------
// K3 k_post: 133 blocks x 256 (4 waves). Coalesced stage reduce (waves 0-1 =
// half L, 2-3 = half R; each wave-iter reads 2 full rows = 256B contiguous),
// then gcn projection -> MLP + residual + LayerNorm(ddof=1) -> QG/SG.
// ---------------------------------------------------------------------------
__global__ __launch_bounds__(256) void k_post(
    const float* __restrict__ gcn_w, const float* __restrict__ gcn_wb,
    const float* __restrict__ gcn_b,
    const float* __restrict__ qld, const float* __restrict__ qrd,
    const float* __restrict__ sld, const float* __restrict__ srd,
    const float* __restrict__ w1, const float* __restrict__ b1,
    const float* __restrict__ w2, const float* __restrict__ b2,
    const float* __restrict__ lng, const float* __restrict__ lnb,
    float* __restrict__ ws)
{
    const int blk = blockIdx.x, t = threadIdx.x;
    const unsigned* stage_u = (const unsigned*)(ws + OFF_STAGE);

    __shared__ float2 mmw[4][32];
    __shared__ float  mm[128];
    __shared__ float  degs[2];
    __shared__ float  x[128];
    __shared__ float  h1[256];
    __shared__ float  hh[128];
    __shared__ float  red[8];

    if (t < 2) {
        const float* dp;
        if (blk < 128) dp = t ? qrd + blk : qld + blk;
        else           dp = t ? srd + (blk - 128) : sld + (blk - 128);
        degs[t] = dp[0];
    }

    {   // coalesced reduce over 200 edge rows per half
        const int w = t >> 6, lane = t & 63;
        const int half = w >> 1, wl = w & 1;
        const int c = lane & 31, rp = lane >> 5;
        int e0;
        if (blk < 128) e0 = half ? 25600 + blk * 200 : blk * 200;
        else { const int f = blk - 128; e0 = half ? 52200 + f * 200 : 51200 + f * 200; }
        const unsigned* sp = stage_u + (size_t)e0 * 32 + (wl * 2 + rp) * 32 + c;
        float slo = 0.f, shi = 0.f;
#pragma unroll 10
        for (int it = 0; it < 50; ++it) {
            const unsigned u = sp[it * 128];
            slo += bflo(u);
            shi += bfhi(u);
        }
        slo += __shfl_xor(slo, 32);
        shi += __shfl_xor(shi, 32);
        if (rp == 0) mmw[w][c] = make_float2(slo, shi);
    }
    __syncthreads();
    if (t < 64) {
        const int half = t >> 5, c = t & 31;
        const float2 a = mmw[half * 2][c], b = mmw[half * 2 + 1][c];
        ((float2*)mm)[half * 32 + c] = make_float2(a.x + b.x, a.y + b.y);
    }
    __syncthreads();

    if (t < 128) {
        const int col = t & 63, base = t & 64;
        float s = 0.f;
#pragma unroll 8
        for (int j = 0; j < 64; ++j) s = fmaf(mm[base + j], gcn_w[j * 64 + col], s);
        s += 200.f * (gcn_wb[col] + gcn_b[col]);
        x[t] = tanhf(s / degs[t >> 6]);
    }
    __syncthreads();

    {
        float s = b1[t];
#pragma unroll 8
        for (int j = 0; j < 128; ++j) s = fmaf(x[j], w1[j * 256 + t], s);
        h1[t] = fmaxf(s, 0.f);
    }
    __syncthreads();
    if (t < 128) {
        float s = b2[t] + x[t];
#pragma unroll 8
        for (int k = 0; k < 256; ++k) s = fmaf(h1[k], w2[k * 128 + t], s);
        hh[t] = s;
    }
    __syncthreads();

    float v = (t < 128) ? hh[t] : 0.f;
#pragma unroll
    for (int m = 32; m >= 1; m >>= 1) v += __shfl_xor(v, m);
    if ((t & 63) == 0) red[t >> 6] = v;
    __syncthreads();
    const float mu = (red[0] + red[1]) * (1.f / 128.f);
    float d = (t < 128) ? (hh[t] - mu) : 0.f;
    float v2 = d * d;
#pragma unroll
    for (int m = 32; m >= 1; m >>= 1) v2 += __shfl_xor(v2, m);
    if ((t & 63) == 0) red[4 + (t >> 6)] = v2;
    __syncthreads();
    const float var = (red[4] + red[5]) * (1.f / 127.f);
    const float rs = 1.f / (sqrtf(var) + 0.001f);
    if (t < 128) {
        float* xout = (blk < 128) ? ws + OFF_QG + blk * 128 : ws + OFF_SG + (blk - 128) * 128;
        xout[t] = (hh[t] - mu) * rs * lng[t] + lnb[t];
    }
}

// ---------------------------------------------------------------------------
// K4 k_lstm: 128 blocks x 512 (one batch row per block). Thread t owns live
// gate unit t (cells 0..127 x {i,f,g,o}); h_r_[:,128:256] is dead in the
// reference. Four independent fma chains over bf16-packed weights.
// ---------------------------------------------------------------------------
__global__ __launch_bounds__(512) void k_lstm(
    const float* __restrict__ bih, const float* __restrict__ bhh,
    float* __restrict__ ws, float* __restrict__ outp)
{
    const int t = threadIdx.x;
    const int b = blockIdx.x;
    const unsigned* whhp = (const unsigned*)(ws + OFF_WHHP);
    const unsigned* wihp = (const unsigned*)(ws + OFF_WIHP);

    __shared__ float sgf[5 * 128];
    __shared__ float qg[128];
    __shared__ float hr[256];
    __shared__ float gbuf[512];
    __shared__ float redw[2][5];

    for (int i = t; i < 640; i += 512) sgf[i] = (ws + OFF_SG)[i];
    if (t < 128) qg[t] = (ws + OFF_QG)[(size_t)b * 128 + t];
    if (t < 256) hr[t] = 0.f;

    const int u = ((t >> 7) << 8) + (t & 127);
    float xp = bih[u] + bhh[u];
    __syncthreads();

    const float2* qg2 = (const float2*)qg;
    const float2* hr2 = (const float2*)hr;

#pragma unroll 8
    for (int jp = 0; jp < 64; ++jp) {
        const unsigned w = wihp[jp * 512 + t];
        const float2 q = qg2[jp];
        xp = fmaf(bflo(w), q.x, fmaf(bfhi(w), q.y, xp));
    }

    float c = 0.f;
    const int tp = t & 127;

    for (int step = 0; step < 4; ++step) {
        float g0 = xp, g1 = 0.f, g2 = 0.f, g3 = 0.f;
#pragma unroll 4
        for (int jp = 0; jp < 128; jp += 4) {
            const unsigned w0 = whhp[(jp + 0) * 512 + t];
            const unsigned w1 = whhp[(jp + 1) * 512 + t];
            const unsigned w2 = whhp[(jp + 2) * 512 + t];
            const unsigned w3 = whhp[(jp + 3) * 512 + t];
            const float2 h0 = hr2[jp + 0], h1 = hr2[jp + 1];
            const float2 h2 = hr2[jp + 2], h3 = hr2[jp + 3];
            g0 = fmaf(bflo(w0), h0.x, fmaf(bfhi(w0), h0.y, g0));
            g1 = fmaf(bflo(w1), h1.x, fmaf(bfhi(w1), h1.y, g1));
            g2 = fmaf(bflo(w2), h2.x, fmaf(bfhi(w2), h2.y, g2));
            g3 = fmaf(bflo(w3), h3.x, fmaf(bfhi(w3), h3.y, g3));
        }
        gbuf[t] = (g0 + g1) + (g2 + g3);
        __syncthreads();

        float hv = 0.f;
        if (t < 128) {
            const float iv = sigm(gbuf[tp]);
            const float fv = sigm(gbuf[128 + tp]);
            const float gv = tanhf(gbuf[256 + tp]);
            const float ov = sigm(gbuf[384 + tp]);
            c = fv * c + iv * gv;
            hv = qg[tp] + ov * tanhf(c);
            hr[tp] = hv;
        }

        float p0 = 0, p1 = 0, p2 = 0, p3 = 0, p4 = 0;
        if (t < 128) {
            p0 = hv * sgf[0 * 128 + tp];
            p1 = hv * sgf[1 * 128 + tp];
            p2 = hv * sgf[2 * 128 + tp];
            p3 = hv * sgf[3 * 128 + tp];
            p4 = hv * sgf[4 * 128 + tp];
#pragma unroll
            for (int m = 32; m >= 1; m >>= 1) {
                p0 += __shfl_xor(p0, m);
                p1 += __shfl_xor(p1, m);
                p2 += __shfl_xor(p2, m);
                p3 += __shfl_xor(p3, m);
                p4 += __shfl_xor(p4, m);
            }
            if ((t & 63) == 0) {
                const int w = t >> 6;
                redw[w][0] = p0; redw[w][1] = p1; redw[w][2] = p2;
                redw[w][3] = p3; redw[w][4] = p4;
            }
        }
        __syncthreads();

        const float d0 = redw[0][0] + redw[1][0];
        const float d1 = redw[0][1] + redw[1][1];
        const float d2 = redw[0][2] + redw[1][2];
        const float d3 = redw[0][3] + redw[1][3];
        const float d4 = redw[0][4] + redw[1][4];

        if (step == 3) {
            if (t == 0) {
                float* o = outp + (size_t)b * 5;
                o[0] = d0; o[1] = d1; o[2] = d2; o[3] = d3; o[4] = d4;
            }
        }
        if (t < 128) {
            const float mx = fmaxf(fmaxf(fmaxf(d0, d1), fmaxf(d2, d3)), d4);
            const float e0 = __expf(d0 - mx), e1 = __expf(d1 - mx), e2 = __expf(d2 - mx),
                        e3 = __expf(d3 - mx), e4 = __expf(d4 - mx);
            const float inv = 1.f / (e0 + e1 + e2 + e3 + e4);
            hr[128 + tp] = (e0 * sgf[0 * 128 + tp] + e1 * sgf[1 * 128 + tp] +
                            e2 * sgf[2 * 128 + tp] + e3 * sgf[3 * 128 + tp] +
                            e4 * sgf[4 * 128 + tp]) * inv;
        }
        __syncthreads();
    }
}

// ---------------------------------------------------------------------------
extern "C" void kernel_launch(void* const* d_in, const int* in_sizes, int n_in,
                              void* d_out, int out_size, void* d_ws, size_t ws_size,
                              hipStream_t stream) {
    const int*   qlc = (const int*)d_in[0];
    const int*   qrc = (const int*)d_in[1];
    const int*   slc = (const int*)d_in[2];
    const int*   srcn= (const int*)d_in[3];
    const float* qld = (const float*)d_in[4];
    const float* qrd = (const float*)d_in[5];
    const float* sld = (const float*)d_in[6];
    const float* srd = (const float*)d_in[7];
    const float* ent = (const float*)d_in[8];
    const float* rel = (const float*)d_in[9];
    const float* gw  = (const float*)d_in[10];
    const float* gwb = (const float*)d_in[11];
    const float* gb  = (const float*)d_in[12];
    const float* w1  = (const float*)d_in[13];
    const float* b1  = (const float*)d_in[14];
    const float* w2  = (const float*)d_in[15];
    const float* b2  = (const float*)d_in[16];
    const float* lng = (const float*)d_in[17];
    const float* lnb = (const float*)d_in[18];
    const float* wih = (const float*)d_in[19];
    const float* whh = (const float*)d_in[20];
    const float* bih = (const float*)d_in[21];
    const float* bhh = (const float*)d_in[22];

    float* ws   = (float*)d_ws;
    float* outp = (float*)d_out;

    hipLaunchKernelGGL(k_prep,   dim3(296), dim3(512), 0, stream,
                       qlc, qrc, slc, srcn, whh, wih, ws);
    hipLaunchKernelGGL(k_gather, dim3(NREL), dim3(512), 0, stream, rel, ent, ws);
    hipLaunchKernelGGL(k_post,   dim3(133), dim3(256), 0, stream,
                       gw, gwb, gb, qld, qrd, sld, srd,
                       w1, b1, w2, b2, lng, lnb, ws);
    hipLaunchKernelGGL(k_lstm,   dim3(128), dim3(512), 0, stream, bih, bhh, ws, outp);
}